// Round 6
// baseline (364.929 us; speedup 1.0000x reference)
//
#include <hip/hip_runtime.h>
#include <hip/hip_bf16.h>

typedef unsigned short u16;
typedef __attribute__((ext_vector_type(8))) short short8;   // 8 x bf16 bits
typedef __attribute__((ext_vector_type(4))) short short4v;  // 4 x bf16 bits
typedef __attribute__((ext_vector_type(4))) float f32x4;

#define S_DIM 2048
#define D_DIM 2048
#define H_NUM 16
#define DH_NUM 64

#if __has_builtin(__builtin_amdgcn_exp2f)
#define EXP2(x) __builtin_amdgcn_exp2f(x)
#else
#define EXP2(x) exp2f(x)
#endif

__device__ __forceinline__ u16 f2bf(float f) {
    union { float f; unsigned u; } x; x.f = f;
    unsigned r = x.u + 0x7fff + ((x.u >> 16) & 1);   // RNE
    return (u16)(r >> 16);
}

// pack 2 fp32 -> 2 bf16 (RNE) in one v_cvt_pk_bf16_f32
__device__ __forceinline__ unsigned pk_bf16(float a, float b) {
    union { __hip_bfloat162 h; unsigned u; } cv;
    float2 t; t.x = a; t.y = b;
    cv.h = __float22bfloat162_rn(t);
    return cv.u;
}

// register-pair lane swaps (gfx950): after swap32, a=[A0 A1 B0 B1], b=[A2 A3 B2 B3]
// (Ag = 16-lane group g of a). after swap16 on that: a=[A0 A2 B0 B2], b=[A1 A3 B1 B3].
__device__ __forceinline__ void lane_swap32(unsigned &a, unsigned &b) {
    asm("v_permlane32_swap_b32 %0, %1" : "+v"(a), "+v"(b));
}
__device__ __forceinline__ void lane_swap16(unsigned &a, unsigned &b) {
    asm("v_permlane16_swap_b32 %0, %1" : "+v"(a), "+v"(b));
}

// async global->LDS, 16B per lane; LDS dest = wave-uniform base + lane*16
__device__ __forceinline__ void gload16(const void* g, void* l) {
    __builtin_amdgcn_global_load_lds(
        (const __attribute__((address_space(1))) unsigned int*)g,
        (__attribute__((address_space(3))) unsigned int*)l, 16, 0, 0);
}

// ---------------------------------------------------------------------------
// Fast transpose body: 64x64 fp32 LDS tile, float4 reads, 16B bf16 stores.
// ---------------------------------------------------------------------------
__device__ __forceinline__ void transpose_body(const float* __restrict__ src,
                                               u16* __restrict__ dst,
                                               int tx, int ty, int t)
{
    __shared__ float tile[64][65];
    const int r0 = ty * 64, c0 = tx * 64;
#pragma unroll
    for (int p = 0; p < 4; ++p) {
        int r = p * 16 + (t >> 4), c = (t & 15) * 4;
        float4 v = *(const float4*)&src[(long)(r0 + r) * D_DIM + c0 + c];
        tile[r][c] = v.x; tile[r][c + 1] = v.y;
        tile[r][c + 2] = v.z; tile[r][c + 3] = v.w;
    }
    __syncthreads();
#pragma unroll
    for (int p = 0; p < 2; ++p) {
        int ch = t + p * 256;
        int i = ch >> 3, j0 = (ch & 7) * 8;
        short8 o;
#pragma unroll
        for (int jj = 0; jj < 8; ++jj)
            o[jj] = (short)f2bf(tile[j0 + jj][i]);
        *(short8*)&dst[(long)(c0 + i) * D_DIM + r0 + j0] = o;
    }
}

__global__ __launch_bounds__(256)
void transpose_fast(const float* __restrict__ src, u16* __restrict__ dst)
{
    transpose_body(src, dst, blockIdx.x, blockIdx.y, threadIdx.x);
}

// fused prep: z=0 cvt x->bf16, z=1..3 W^T (q/k/v), z=4 (optional) Wo^T
__global__ __launch_bounds__(256)
void prep4(const float* __restrict__ x,
           const float* __restrict__ Wq, const float* __restrict__ Wk,
           const float* __restrict__ Wv, const float* __restrict__ Wo,
           u16* __restrict__ XB, u16* T0, u16* T1, u16* T2, u16* T3)
{
    const int z = blockIdx.z, t = threadIdx.x, bx = blockIdx.x;
    if (z == 0) {
        long i0 = ((long)bx * 256 + t) * 16;
        short8 o0, o1;
#pragma unroll
        for (int j = 0; j < 2; ++j) {
            float4 a = *(const float4*)&x[i0 + j * 8];
            float4 b = *(const float4*)&x[i0 + j * 8 + 4];
            short8& o = j ? o1 : o0;
            o[0] = (short)f2bf(a.x); o[1] = (short)f2bf(a.y);
            o[2] = (short)f2bf(a.z); o[3] = (short)f2bf(a.w);
            o[4] = (short)f2bf(b.x); o[5] = (short)f2bf(b.y);
            o[6] = (short)f2bf(b.z); o[7] = (short)f2bf(b.w);
        }
        *(short8*)&XB[i0] = o0;
        *(short8*)&XB[i0 + 8] = o1;
    } else {
        const float* src = (z == 1) ? Wq : (z == 2) ? Wk : (z == 3) ? Wv : Wo;
        u16* dst         = (z == 1) ? T0 : (z == 2) ? T1 : (z == 3) ? T2 : T3;
        transpose_body(src, dst, bx & 31, bx >> 5, t);
    }
}

__global__ __launch_bounds__(256)
void cvt_bf16(const float* __restrict__ src, u16* __restrict__ dst)
{
    int i = (blockIdx.x * 256 + threadIdx.x) * 4;
    float4 v = *(const float4*)(src + i);
    ushort4 o;
    o.x = f2bf(v.x); o.y = f2bf(v.y); o.z = f2bf(v.z); o.w = f2bf(v.w);
    *(ushort4*)(dst + i) = o;
}

// ---------------------------------------------------------------------------
// 128x128-tile GEMM, BK=64, r16: single-buffered m97-proven 2-barrier loop,
// __launch_bounds__(256,3): LDS 32 KB -> 3 blocks/CU, and the 16x16x3 = 768
// block grid is EXACTLY 256 CU x 3 -> whole grid co-resident, no dispatch
// rounds, no tail, 12 waves/CU of cross-block latency hiding (r15's dbuf
// 64 KB capped at 2 blocks/CU and measured null). XOR-chunk swizzle staging:
// LDS slot s of row r holds global chunk s^(r&7); rows are 128B so bank =
// slot -> b128 reads 2-way (free). z0 -> Q (scaled 1/8*log2e), z1 -> K,
// z2 -> V^T via operand-swapped MFMA (contig stores).
// ---------------------------------------------------------------------------
__global__ __launch_bounds__(256, 3)
void gemm128(const u16* __restrict__ A,
             const u16* B0, const u16* B1, const u16* B2,
             u16* C0, u16* C1, u16* C2, int zbase)
{
    const int Kd = D_DIM, N = D_DIM, M = S_DIM;
    const int z = blockIdx.z + zbase;
    const u16* Bt = (z == 0) ? B0 : (z == 1) ? B1 : B2;
    u16* C        = (z == 0) ? C0 : (z == 1) ? C1 : C2;

    __shared__ __attribute__((aligned(16))) u16 As[128 * 64];
    __shared__ __attribute__((aligned(16))) u16 Bs[128 * 64];

    const int tid = threadIdx.x, lane = tid & 63, wave = tid >> 6;
    const int bm = blockIdx.x * 128, bn = blockIdx.y * 128;

    // staging: wave covers rows wave*32..+31 (4 groups of 8 rows);
    // lane -> row group + (lane>>3), global chunk ((lane&7)^(lane>>3))
    const int grow = lane >> 3;
    const int gcol = ((lane & 7) ^ grow) * 8;

    const int wr = (wave >> 1) * 64, wc = (wave & 1) * 64;
    const int fr = lane & 15, fq = lane >> 4;
    const int swz = fr & 7;

    f32x4 acc[4][4];
    for (int i = 0; i < 4; ++i)
        for (int j = 0; j < 4; ++j) { f32x4 zz = {0.f,0.f,0.f,0.f}; acc[i][j] = zz; }

    for (int k0 = 0; k0 < Kd; k0 += 64) {
#pragma unroll
        for (int g = 0; g < 4; ++g) {
            int r = wave * 32 + g * 8;
            gload16(A + (long)(bm + r + grow) * Kd + k0 + gcol, &As[r * 64]);
            gload16(Bt + (long)(bn + r + grow) * Kd + k0 + gcol, &Bs[r * 64]);
        }
        __syncthreads();

#pragma unroll
        for (int ks = 0; ks < 2; ++ks) {
            const int slot = ((fq + ks * 4) ^ swz) * 8;
            short8 af[4], bf[4];
#pragma unroll
            for (int i = 0; i < 4; ++i) {
                af[i] = *(const short8*)&As[(wr + i * 16 + fr) * 64 + slot];
                bf[i] = *(const short8*)&Bs[(wc + i * 16 + fr) * 64 + slot];
            }
            if (z == 2) {
#pragma unroll
                for (int i = 0; i < 4; ++i)
#pragma unroll
                    for (int j = 0; j < 4; ++j)
                        acc[i][j] = __builtin_amdgcn_mfma_f32_16x16x32_bf16(bf[j], af[i], acc[i][j], 0, 0, 0);
            } else {
#pragma unroll
                for (int i = 0; i < 4; ++i)
#pragma unroll
                    for (int j = 0; j < 4; ++j)
                        acc[i][j] = __builtin_amdgcn_mfma_f32_16x16x32_bf16(af[i], bf[j], acc[i][j], 0, 0, 0);
            }
        }
        __syncthreads();
    }

    if (z == 2) {
        // swapped layout: row (fq*4+r) = channel, col (fr) = token -> contig
#pragma unroll
        for (int i = 0; i < 4; ++i) {
            int tok = bm + wr + i * 16 + fr;
#pragma unroll
            for (int j = 0; j < 4; ++j) {
                int ch = bn + wc + j * 16 + fq * 4;
#pragma unroll
                for (int r = 0; r < 4; ++r)
                    C[(long)(ch + r) * M + tok] = f2bf(acc[i][j][r]);
            }
        }
    } else {
        const float sc = (z == 0) ? 0.125f * 1.44269504f : 1.0f;  // Q log2-domain
#pragma unroll
        for (int i = 0; i < 4; ++i) {
            int row = bm + wr + i * 16 + fq * 4;
#pragma unroll
            for (int j = 0; j < 4; ++j) {
                int col = bn + wc + j * 16 + fr;
#pragma unroll
                for (int r = 0; r < 4; ++r)
                    C[(long)(row + r) * N + col] = f2bf(acc[i][j][r] * sc);
            }
        }
    }
}

// ---------------------------------------------------------------------------
// 64x64-tile GEMM, fp32 output, BK=64. r16 rebuild: grid 32x32 = 1024 blocks
// = 256 CU x 4 exact fill (old 64x128 had 2x4 acc at 2 blocks/CU and was
// latency-exposed). 4 waves of 32x32 quadrants, acc 2x2/wave, LDS 16 KB
// single-buffered -> 4 blocks/CU = 16 waves/CU TLP. Same XOR-chunk staging.
// ---------------------------------------------------------------------------
__global__ __launch_bounds__(256, 4)
void gemm_out(const u16* __restrict__ A, const u16* __restrict__ Bt,
              float* __restrict__ C)
{
    const int Kd = D_DIM, N = D_DIM;

    __shared__ __attribute__((aligned(16))) u16 As[64 * 64];
    __shared__ __attribute__((aligned(16))) u16 Bs[64 * 64];

    const int tid = threadIdx.x, lane = tid & 63, wave = tid >> 6;
    const int bm = blockIdx.x * 64, bn = blockIdx.y * 64;

    const int grow = lane >> 3;
    const int gcol = ((lane & 7) ^ grow) * 8;

    const int wr = (wave >> 1) * 32, wc = (wave & 1) * 32;
    const int fr = lane & 15, fq = lane >> 4;
    const int swz = fr & 7;

    f32x4 acc[2][2];
    for (int i = 0; i < 2; ++i)
        for (int j = 0; j < 2; ++j) { f32x4 zz = {0.f,0.f,0.f,0.f}; acc[i][j] = zz; }

    for (int k0 = 0; k0 < Kd; k0 += 64) {
#pragma unroll
        for (int g = 0; g < 2; ++g) {
            int r = wave * 16 + g * 8;
            gload16(A + (long)(bm + r + grow) * Kd + k0 + gcol, &As[r * 64]);
            gload16(Bt + (long)(bn + r + grow) * Kd + k0 + gcol, &Bs[r * 64]);
        }
        __syncthreads();

#pragma unroll
        for (int ks = 0; ks < 2; ++ks) {
            const int slot = ((fq + ks * 4) ^ swz) * 8;
            short8 af[2], bf[2];
#pragma unroll
            for (int i = 0; i < 2; ++i) {
                af[i] = *(const short8*)&As[(wr + i * 16 + fr) * 64 + slot];
                bf[i] = *(const short8*)&Bs[(wc + i * 16 + fr) * 64 + slot];
            }
#pragma unroll
            for (int i = 0; i < 2; ++i)
#pragma unroll
                for (int j = 0; j < 2; ++j)
                    acc[i][j] = __builtin_amdgcn_mfma_f32_16x16x32_bf16(af[i], bf[j], acc[i][j], 0, 0, 0);
        }
        __syncthreads();
    }

#pragma unroll
    for (int i = 0; i < 2; ++i) {
        int row = bm + wr + i * 16 + fq * 4;
#pragma unroll
        for (int j = 0; j < 2; ++j) {
            int col = bn + wc + j * 16 + fr;
#pragma unroll
            for (int r = 0; r < 4; ++r)
                C[(long)(row + r) * N + col] = acc[i][j][r];
        }
    }
}

// ---------------------------------------------------------------------------
// Differential flash attention + fused GroupNorm — r12-PROVEN version
// (80.0 µs, 0 bank conflicts, VGPR 88, 2 blocks/CU). 4 waves x 16q, full
// 64-key tiles, global_load_lds staging with XOR-chunk swizzle, K=32 PV via
// permlane merge, exp2-domain softmax, fused GN epilogue.
// ---------------------------------------------------------------------------
__global__ __launch_bounds__(256, 2)
void diff_attn(const u16* __restrict__ Qm, const u16* __restrict__ Km,
               const u16* __restrict__ Vt,
               const float* __restrict__ lq1, const float* __restrict__ lk1,
               const float* __restrict__ lq2, const float* __restrict__ lk2,
               const float* __restrict__ gw, const float* __restrict__ gb,
               u16* __restrict__ Y)
{
    __shared__ __attribute__((aligned(16))) u16 K1s[2][64 * 64];
    __shared__ __attribute__((aligned(16))) u16 K2s[2][64 * 64];
    __shared__ __attribute__((aligned(16))) u16 Vts[2][128 * 64];

    const int tid = threadIdx.x, lane = tid & 63, wave = tid >> 6;
    const int h = blockIdx.y;
    const int q0 = blockIdx.x * 64 + wave * 16;
    const int fr = lane & 15, qq = lane >> 4;
    const int fsw = fr & 7;

    const int grow = lane >> 3;
    const int gcol = ((lane & 7) ^ grow) * 8;

    float d1 = 0.f, d2 = 0.f;
    for (int i = 0; i < DH_NUM; ++i) {
        d1 += lq1[i] * lk1[i];
        d2 += lq2[i] * lk2[i];
    }
    const float lam = __expf(d1) - __expf(d2) + 0.8f;

    short8 q1f[2], q2f[2];
    {
        const u16* qb = Qm + (long)(q0 + fr) * D_DIM + h * 128;
        q1f[0] = *(const short8*)(qb + qq * 8);
        q1f[1] = *(const short8*)(qb + 32 + qq * 8);
        q2f[0] = *(const short8*)(qb + 64 + qq * 8);
        q2f[1] = *(const short8*)(qb + 96 + qq * 8);
    }

    f32x4 a1[8], a2[8];
    for (int n = 0; n < 8; ++n) { f32x4 zz = {0.f,0.f,0.f,0.f}; a1[n] = zz; a2[n] = zz; }
    float ls1 = 0.f, ls2 = 0.f;

    auto stage = [&](int kb, int b) {
        const long kbase = (long)(kb * 64) * D_DIM + h * 128;
#pragma unroll
        for (int g = 0; g < 2; ++g) {
            int r = wave * 16 + g * 8;
            gload16(Km + kbase + (long)(r + grow) * D_DIM + gcol,      &K1s[b][r * 64]);
            gload16(Km + kbase + (long)(r + grow) * D_DIM + 64 + gcol, &K2s[b][r * 64]);
        }
#pragma unroll
        for (int g = 0; g < 4; ++g) {
            int c = wave * 32 + g * 8;
            gload16(Vt + (long)(h * 128 + c + grow) * S_DIM + kb * 64 + gcol,
                    &Vts[b][c * 64]);
        }
    };

    stage(0, 0);
    int p = 0;

    for (int kb = 0; kb < S_DIM / 64; ++kb) {
        __syncthreads();                       // tile p staged & prev reads done
        const bool more = (kb + 1 < S_DIM / 64);
        if (more) stage(kb + 1, p ^ 1);        // prefetch hides under compute

        // jj indexes a 32-key window; jh its two 16-key S-chunks.
#pragma unroll
        for (int jj = 0; jj < 2; ++jj) {
            unsigned u1[2][2], u2[2][2];   // [jh][packed word]; all const-indexed
#pragma unroll
            for (int jh = 0; jh < 2; ++jh) {
                const int j = jj * 2 + jh;
                f32x4 s1 = {0.f,0.f,0.f,0.f}, s2 = {0.f,0.f,0.f,0.f};
#pragma unroll
                for (int ks = 0; ks < 2; ++ks) {
                    const int slot = ((ks * 4 + qq) ^ fsw) * 8;
                    short8 k1 = *(const short8*)&K1s[p][(j * 16 + fr) * 64 + slot];
                    short8 k2 = *(const short8*)&K2s[p][(j * 16 + fr) * 64 + slot];
                    s1 = __builtin_amdgcn_mfma_f32_16x16x32_bf16(k1, q1f[ks], s1, 0, 0, 0);
                    s2 = __builtin_amdgcn_mfma_f32_16x16x32_bf16(k2, q2f[ks], s2, 0, 0, 0);
                }
                float e1[4], e2[4];
#pragma unroll
                for (int r = 0; r < 4; ++r) {
                    e1[r] = EXP2(s1[r]);            // Q pre-scaled by log2e
                    e2[r] = EXP2(s2[r]);
                    ls1 += e1[r]; ls2 += e2[r];
                }
                u1[jh][0] = pk_bf16(e1[0], e1[1]); u1[jh][1] = pk_bf16(e1[2], e1[3]);
                u2[jh][0] = pk_bf16(e2[0], e2[1]); u2[jh][1] = pk_bf16(e2[2], e2[3]);
            }

            // Merge two 16-key P-chunks into K=32 B-fragments.
            // Lane group g holds keys {4g,4g+1}(w0)/{4g+2,4g+3}(w1) per chunk;
            // K=32 B-frag word w needs keys {8g+2w, 8g+2w+1}.
            // swap32+swap16 on (chunk0.w, chunk1.w) yields frag words w and w+2.
            union { short8 s; unsigned u[4]; } F1, F2;
            {
                unsigned x = u1[0][0], y = u1[1][0];
                lane_swap32(x, y); lane_swap16(x, y);
                F1.u[0] = x; F1.u[2] = y;
            }
            {
                unsigned x = u1[0][1], y = u1[1][1];
                lane_swap32(x, y); lane_swap16(x, y);
                F1.u[1] = x; F1.u[3] = y;
            }
            {
                unsigned x = u2[0][0], y = u2[1][0];
                lane_swap32(x, y); lane_swap16(x, y);
                F2.u[0] = x; F2.u[2] = y;
            }
            {
                unsigned x = u2[0][1], y = u2[1][1];
                lane_swap32(x, y); lane_swap16(x, y);
                F2.u[1] = x; F2.u[3] = y;
            }

            const int slotV = ((jj * 4 + qq) ^ fsw) * 8;
            __builtin_amdgcn_s_setprio(1);
#pragma unroll
            for (int n = 0; n < 8; ++n) {
                short8 vf = *(const short8*)&Vts[p][(n * 16 + fr) * 64 + slotV];
                a1[n] = __builtin_amdgcn_mfma_f32_16x16x32_bf16(vf, F1.s, a1[n], 0, 0, 0);
                a2[n] = __builtin_amdgcn_mfma_f32_16x16x32_bf16(vf, F2.s, a2[n], 0, 0, 0);
            }
            __builtin_amdgcn_s_setprio(0);
        }

        p ^= 1;
    }

    float L1 = ls1, L2 = ls2;
    L1 += __shfl_xor(L1, 16, 64); L1 += __shfl_xor(L1, 32, 64);
    L2 += __shfl_xor(L2, 16, 64); L2 += __shfl_xor(L2, 32, 64);
    const float i1 = 1.f / L1, i2 = lam / L2;

    float o[8][4], sum = 0.f, sq = 0.f;
#pragma unroll
    for (int n = 0; n < 8; ++n)
#pragma unroll
        for (int r = 0; r < 4; ++r) {
            float v = a1[n][r] * i1 - a2[n][r] * i2;
            o[n][r] = v; sum += v; sq += v * v;
        }
    sum += __shfl_xor(sum, 16, 64); sum += __shfl_xor(sum, 32, 64);
    sq  += __shfl_xor(sq, 16, 64);  sq  += __shfl_xor(sq, 32, 64);
    const float mean = sum * (1.f / 128.f);
    const float var = sq * (1.f / 128.f) - mean * mean;
    const float inv = rsqrtf(var + 1e-5f);

    const long yrow = (long)(q0 + fr) * D_DIM + h * 128;
#pragma unroll
    for (int n = 0; n < 8; ++n) {
        float4 g4 = *(const float4*)&gw[h * 128 + n * 16 + qq * 4];
        float4 b4 = *(const float4*)&gb[h * 128 + n * 16 + qq * 4];
        ushort4 st;
        st.x = f2bf(((o[n][0] - mean) * inv * g4.x + b4.x) * 0.2f);
        st.y = f2bf(((o[n][1] - mean) * inv * g4.y + b4.y) * 0.2f);
        st.z = f2bf(((o[n][2] - mean) * inv * g4.z + b4.z) * 0.2f);
        st.w = f2bf(((o[n][3] - mean) * inv * g4.w + b4.w) * 0.2f);
        *(ushort4*)&Y[yrow + n * 16 + qq * 4] = st;
    }
}

// ---------------------------------------------------------------------------
extern "C" void kernel_launch(void* const* d_in, const int* in_sizes, int n_in,
                              void* d_out, int out_size, void* d_ws, size_t ws_size,
                              hipStream_t stream)
{
    const float* x   = (const float*)d_in[0];
    const float* Wq  = (const float*)d_in[1];
    const float* Wk  = (const float*)d_in[2];
    const float* Wv  = (const float*)d_in[3];
    const float* Wo  = (const float*)d_in[4];
    const float* lq1 = (const float*)d_in[5];
    const float* lk1 = (const float*)d_in[6];
    const float* lq2 = (const float*)d_in[7];
    const float* lk2 = (const float*)d_in[8];
    const float* gw  = (const float*)d_in[9];
    const float* gb  = (const float*)d_in[10];

    char* ws = (char*)d_ws;
    const size_t SEG = (size_t)D_DIM * D_DIM * sizeof(u16);   // 8 MiB
    const dim3 tgrid(32, 32), agrid(32, 16), ogrid(32, 32);

    if (ws_size >= 8 * SEG) {
        u16* XB  = (u16*)(ws + 0 * SEG);
        u16* WTq = (u16*)(ws + 1 * SEG);
        u16* WTk = (u16*)(ws + 2 * SEG);
        u16* WTv = (u16*)(ws + 3 * SEG);
        u16* Qb  = (u16*)(ws + 4 * SEG);
        u16* Kb  = (u16*)(ws + 5 * SEG);
        u16* Vt  = (u16*)(ws + 6 * SEG);
        u16* WTo = (u16*)(ws + 7 * SEG);
        u16* Yb  = WTk;   // dead after QKV GEMM

        prep4<<<dim3(1024, 1, 5), 256, 0, stream>>>(x, Wq, Wk, Wv, Wo,
                                                    XB, WTq, WTk, WTv, WTo);
        gemm128<<<dim3(16, 16, 3), 256, 0, stream>>>(XB, WTq, WTk, WTv,
                                                     Qb, Kb, Vt, 0);
        diff_attn<<<agrid, 256, 0, stream>>>(Qb, Kb, Vt, lq1, lk1, lq2, lk2,
                                             gw, gb, Yb);
        gemm_out<<<ogrid, 256, 0, stream>>>(Yb, WTo, (float*)d_out);
    } else if (ws_size >= 7 * SEG) {
        u16* XB  = (u16*)(ws + 0 * SEG);
        u16* WTq = (u16*)(ws + 1 * SEG);
        u16* WTk = (u16*)(ws + 2 * SEG);
        u16* WTv = (u16*)(ws + 3 * SEG);
        u16* Qb  = (u16*)(ws + 4 * SEG);
        u16* Kb  = (u16*)(ws + 5 * SEG);
        u16* Vt  = (u16*)(ws + 6 * SEG);
        u16* WTo = WTq;   // dead after QKV GEMM
        u16* Yb  = WTk;   // dead after QKV GEMM

        prep4<<<dim3(1024, 1, 4), 256, 0, stream>>>(x, Wq, Wk, Wv, Wo,
                                                    XB, WTq, WTk, WTv, WTq);
        gemm128<<<dim3(16, 16, 3), 256, 0, stream>>>(XB, WTq, WTk, WTv,
                                                     Qb, Kb, Vt, 0);
        transpose_fast<<<tgrid, 256, 0, stream>>>(Wo, WTo);
        diff_attn<<<agrid, 256, 0, stream>>>(Qb, Kb, Vt, lq1, lk1, lq2, lk2,
                                             gw, gb, Yb);
        gemm_out<<<ogrid, 256, 0, stream>>>(Yb, WTo, (float*)d_out);
    } else {
        u16* XB = (u16*)(ws + 0 * SEG);
        u16* WT = (u16*)(ws + 1 * SEG);
        u16* Qb = (u16*)(ws + 2 * SEG);
        u16* Kb = (u16*)(ws + 3 * SEG);
        u16* Vt = (u16*)(ws + 4 * SEG);

        cvt_bf16<<<4096, 256, 0, stream>>>(x, XB);
        transpose_fast<<<tgrid, 256, 0, stream>>>(Wq, WT);
        gemm128<<<dim3(16, 16, 1), 256, 0, stream>>>(XB, WT, WT, WT, Qb, Qb, Qb, 0);
        transpose_fast<<<tgrid, 256, 0, stream>>>(Wk, WT);
        gemm128<<<dim3(16, 16, 1), 256, 0, stream>>>(XB, WT, WT, WT, Kb, Kb, Kb, 1);
        transpose_fast<<<tgrid, 256, 0, stream>>>(Wv, WT);
        gemm128<<<dim3(16, 16, 1), 256, 0, stream>>>(XB, WT, WT, WT, Vt, Vt, Vt, 2);
        diff_attn<<<agrid, 256, 0, stream>>>(Qb, Kb, Vt, lq1, lk1, lq2, lk2,
                                             gw, gb, XB);
        transpose_fast<<<tgrid, 256, 0, stream>>>(Wo, WT);
        gemm_out<<<ogrid, 256, 0, stream>>>(XB, WT, (float*)d_out);
    }
}

// Round 7
// 324.680 us; speedup vs baseline: 1.1240x; 1.1240x over previous
//
#include <hip/hip_runtime.h>
#include <hip/hip_bf16.h>

typedef unsigned short u16;
typedef __attribute__((ext_vector_type(8))) short short8;   // 8 x bf16 bits
typedef __attribute__((ext_vector_type(4))) short short4v;  // 4 x bf16 bits
typedef __attribute__((ext_vector_type(4))) float f32x4;

#define S_DIM 2048
#define D_DIM 2048
#define H_NUM 16
#define DH_NUM 64

#if __has_builtin(__builtin_amdgcn_exp2f)
#define EXP2(x) __builtin_amdgcn_exp2f(x)
#else
#define EXP2(x) exp2f(x)
#endif

__device__ __forceinline__ u16 f2bf(float f) {
    union { float f; unsigned u; } x; x.f = f;
    unsigned r = x.u + 0x7fff + ((x.u >> 16) & 1);   // RNE
    return (u16)(r >> 16);
}

// pack 2 fp32 -> 2 bf16 (RNE) in one v_cvt_pk_bf16_f32
__device__ __forceinline__ unsigned pk_bf16(float a, float b) {
    union { __hip_bfloat162 h; unsigned u; } cv;
    float2 t; t.x = a; t.y = b;
    cv.h = __float22bfloat162_rn(t);
    return cv.u;
}

// register-pair lane swaps (gfx950): after swap32, a=[A0 A1 B0 B1], b=[A2 A3 B2 B3]
// (Ag = 16-lane group g of a). after swap16 on that: a=[A0 A2 B0 B2], b=[A1 A3 B1 B3].
__device__ __forceinline__ void lane_swap32(unsigned &a, unsigned &b) {
    asm("v_permlane32_swap_b32 %0, %1" : "+v"(a), "+v"(b));
}
__device__ __forceinline__ void lane_swap16(unsigned &a, unsigned &b) {
    asm("v_permlane16_swap_b32 %0, %1" : "+v"(a), "+v"(b));
}

// async global->LDS, 16B per lane; LDS dest = wave-uniform base + lane*16
__device__ __forceinline__ void gload16(const void* g, void* l) {
    __builtin_amdgcn_global_load_lds(
        (const __attribute__((address_space(1))) unsigned int*)g,
        (__attribute__((address_space(3))) unsigned int*)l, 16, 0, 0);
}

// ---------------------------------------------------------------------------
// Fast transpose body: 64x64 fp32 LDS tile, float4 reads, 16B bf16 stores.
// ---------------------------------------------------------------------------
__device__ __forceinline__ void transpose_body(const float* __restrict__ src,
                                               u16* __restrict__ dst,
                                               int tx, int ty, int t)
{
    __shared__ float tile[64][65];
    const int r0 = ty * 64, c0 = tx * 64;
#pragma unroll
    for (int p = 0; p < 4; ++p) {
        int r = p * 16 + (t >> 4), c = (t & 15) * 4;
        float4 v = *(const float4*)&src[(long)(r0 + r) * D_DIM + c0 + c];
        tile[r][c] = v.x; tile[r][c + 1] = v.y;
        tile[r][c + 2] = v.z; tile[r][c + 3] = v.w;
    }
    __syncthreads();
#pragma unroll
    for (int p = 0; p < 2; ++p) {
        int ch = t + p * 256;
        int i = ch >> 3, j0 = (ch & 7) * 8;
        short8 o;
#pragma unroll
        for (int jj = 0; jj < 8; ++jj)
            o[jj] = (short)f2bf(tile[j0 + jj][i]);
        *(short8*)&dst[(long)(c0 + i) * D_DIM + r0 + j0] = o;
    }
}

__global__ __launch_bounds__(256)
void transpose_fast(const float* __restrict__ src, u16* __restrict__ dst)
{
    transpose_body(src, dst, blockIdx.x, blockIdx.y, threadIdx.x);
}

// fused prep: z=0 cvt x->bf16, z=1..3 W^T (q/k/v), z=4 (optional) Wo^T
__global__ __launch_bounds__(256)
void prep4(const float* __restrict__ x,
           const float* __restrict__ Wq, const float* __restrict__ Wk,
           const float* __restrict__ Wv, const float* __restrict__ Wo,
           u16* __restrict__ XB, u16* T0, u16* T1, u16* T2, u16* T3)
{
    const int z = blockIdx.z, t = threadIdx.x, bx = blockIdx.x;
    if (z == 0) {
        long i0 = ((long)bx * 256 + t) * 16;
        short8 o0, o1;
#pragma unroll
        for (int j = 0; j < 2; ++j) {
            float4 a = *(const float4*)&x[i0 + j * 8];
            float4 b = *(const float4*)&x[i0 + j * 8 + 4];
            short8& o = j ? o1 : o0;
            o[0] = (short)f2bf(a.x); o[1] = (short)f2bf(a.y);
            o[2] = (short)f2bf(a.z); o[3] = (short)f2bf(a.w);
            o[4] = (short)f2bf(b.x); o[5] = (short)f2bf(b.y);
            o[6] = (short)f2bf(b.z); o[7] = (short)f2bf(b.w);
        }
        *(short8*)&XB[i0] = o0;
        *(short8*)&XB[i0 + 8] = o1;
    } else {
        const float* src = (z == 1) ? Wq : (z == 2) ? Wk : (z == 3) ? Wv : Wo;
        u16* dst         = (z == 1) ? T0 : (z == 2) ? T1 : (z == 3) ? T2 : T3;
        transpose_body(src, dst, bx & 31, bx >> 5, t);
    }
}

__global__ __launch_bounds__(256)
void cvt_bf16(const float* __restrict__ src, u16* __restrict__ dst)
{
    int i = (blockIdx.x * 256 + threadIdx.x) * 4;
    float4 v = *(const float4*)(src + i);
    ushort4 o;
    o.x = f2bf(v.x); o.y = f2bf(v.y); o.z = f2bf(v.z); o.w = f2bf(v.w);
    *(ushort4*)(dst + i) = o;
}

// ---------------------------------------------------------------------------
// 128x128-tile GEMM, BK=64 — r15-proven form (part of the 296.8 µs best):
// double-buffered 2-phase schedule, stage(t+1) issued BEFORE compute(t),
// ONE __syncthreads per K-step; LDS 64 KB, lb(256,2) = 2 blocks/CU.
// r16's lb(256,3) regressed 2x (151 µs, occupancy DROPPED) — do not raise.
// XOR-chunk swizzle staging: LDS slot s of row r holds global chunk s^(r&7);
// rows are 128B so bank = slot -> b128 reads 2-way (free). z0 -> Q (scaled
// 1/8*log2e), z1 -> K, z2 -> V^T via operand-swapped MFMA (contig stores).
// ---------------------------------------------------------------------------
__global__ __launch_bounds__(256, 2)
void gemm128(const u16* __restrict__ A,
             const u16* B0, const u16* B1, const u16* B2,
             u16* C0, u16* C1, u16* C2, int zbase)
{
    const int Kd = D_DIM, N = D_DIM, M = S_DIM;
    const int z = blockIdx.z + zbase;
    const u16* Bt = (z == 0) ? B0 : (z == 1) ? B1 : B2;
    u16* C        = (z == 0) ? C0 : (z == 1) ? C1 : C2;

    __shared__ __attribute__((aligned(16))) u16 As[2][128 * 64];
    __shared__ __attribute__((aligned(16))) u16 Bs[2][128 * 64];

    const int tid = threadIdx.x, lane = tid & 63, wave = tid >> 6;
    const int bm = blockIdx.x * 128, bn = blockIdx.y * 128;

    const int grow = lane >> 3;
    const int gcol = ((lane & 7) ^ grow) * 8;

    const int wr = (wave >> 1) * 64, wc = (wave & 1) * 64;
    const int fr = lane & 15, fq = lane >> 4;
    const int swz = fr & 7;

    f32x4 acc[4][4];
    for (int i = 0; i < 4; ++i)
        for (int j = 0; j < 4; ++j) { f32x4 zz = {0.f,0.f,0.f,0.f}; acc[i][j] = zz; }

    auto stage = [&](int k0, int b) {
#pragma unroll
        for (int g = 0; g < 4; ++g) {
            int r = wave * 32 + g * 8;
            gload16(A + (long)(bm + r + grow) * Kd + k0 + gcol, &As[b][r * 64]);
            gload16(Bt + (long)(bn + r + grow) * Kd + k0 + gcol, &Bs[b][r * 64]);
        }
    };

    stage(0, 0);
    int p = 0;
    const int NT = Kd / 64;

    for (int t = 0; t < NT; ++t) {
        __syncthreads();                    // tile p staged; prev reads done
        if (t + 1 < NT) stage((t + 1) * 64, p ^ 1);   // in flight under compute

#pragma unroll
        for (int ks = 0; ks < 2; ++ks) {
            const int slot = ((fq + ks * 4) ^ swz) * 8;
            short8 af[4], bf[4];
#pragma unroll
            for (int i = 0; i < 4; ++i) {
                af[i] = *(const short8*)&As[p][(wr + i * 16 + fr) * 64 + slot];
                bf[i] = *(const short8*)&Bs[p][(wc + i * 16 + fr) * 64 + slot];
            }
            if (z == 2) {
#pragma unroll
                for (int i = 0; i < 4; ++i)
#pragma unroll
                    for (int j = 0; j < 4; ++j)
                        acc[i][j] = __builtin_amdgcn_mfma_f32_16x16x32_bf16(bf[j], af[i], acc[i][j], 0, 0, 0);
            } else {
#pragma unroll
                for (int i = 0; i < 4; ++i)
#pragma unroll
                    for (int j = 0; j < 4; ++j)
                        acc[i][j] = __builtin_amdgcn_mfma_f32_16x16x32_bf16(af[i], bf[j], acc[i][j], 0, 0, 0);
            }
        }
        p ^= 1;
    }

    if (z == 2) {
        // swapped layout: row (fq*4+r) = channel, col (fr) = token -> contig
#pragma unroll
        for (int i = 0; i < 4; ++i) {
            int tok = bm + wr + i * 16 + fr;
#pragma unroll
            for (int j = 0; j < 4; ++j) {
                int ch = bn + wc + j * 16 + fq * 4;
#pragma unroll
                for (int r = 0; r < 4; ++r)
                    C[(long)(ch + r) * M + tok] = f2bf(acc[i][j][r]);
            }
        }
    } else {
        const float sc = (z == 0) ? 0.125f * 1.44269504f : 1.0f;  // Q log2-domain
#pragma unroll
        for (int i = 0; i < 4; ++i) {
            int row = bm + wr + i * 16 + fq * 4;
#pragma unroll
            for (int j = 0; j < 4; ++j) {
                int col = bn + wc + j * 16 + fr;
#pragma unroll
                for (int r = 0; r < 4; ++r)
                    C[(long)(row + r) * N + col] = f2bf(acc[i][j][r] * sc);
            }
        }
    }
}

// ---------------------------------------------------------------------------
// 64x128-tile GEMM, fp32 output, r17: 2-WAY K-SPLIT. Grid (32,16,2); block z
// accumulates K in [z*1024, z*1024+1024) (16 steps) and atomicAdd's fp32
// partials into C (zeroed via hipMemsetAsync before launch). Doubles block
// parallelism (512 -> 1024 blocks, 2 clean rounds at 2/CU) and halves each
// latency-bound serial staging chain. Two-addend fp32 atomicAdd is
// order-independent (IEEE add commutes) -> deterministic. dbuf 2-phase
// schedule as gemm128, LDS 48 KB, lb(256,2).
// ---------------------------------------------------------------------------
__global__ __launch_bounds__(256, 2)
void gemm_out(const u16* __restrict__ A, const u16* __restrict__ Bt,
              float* __restrict__ C)
{
    const int Kd = D_DIM, N = D_DIM;

    __shared__ __attribute__((aligned(16))) u16 As[2][64 * 64];
    __shared__ __attribute__((aligned(16))) u16 Bs[2][128 * 64];

    const int tid = threadIdx.x, lane = tid & 63, wave = tid >> 6;
    const int bm = blockIdx.x * 64, bn = blockIdx.y * 128;
    const int k0base = blockIdx.z * (Kd / 2);

    const int grow = lane >> 3;
    const int gcol = ((lane & 7) ^ grow) * 8;

    const int wr = (wave >> 1) * 32, wc = (wave & 1) * 64;
    const int fr = lane & 15, fq = lane >> 4;
    const int swz = fr & 7;

    f32x4 acc[2][4];
    for (int i = 0; i < 2; ++i)
        for (int j = 0; j < 4; ++j) { f32x4 zz = {0.f,0.f,0.f,0.f}; acc[i][j] = zz; }

    auto stage = [&](int k0, int b) {
#pragma unroll
        for (int g = 0; g < 2; ++g) {
            int r = wave * 16 + g * 8;
            gload16(A + (long)(bm + r + grow) * Kd + k0 + gcol, &As[b][r * 64]);
        }
#pragma unroll
        for (int g = 0; g < 4; ++g) {
            int r = wave * 32 + g * 8;
            gload16(Bt + (long)(bn + r + grow) * Kd + k0 + gcol, &Bs[b][r * 64]);
        }
    };

    stage(k0base, 0);
    int p = 0;
    const int NT = Kd / 2 / 64;   // 16 steps per K-half

    for (int t = 0; t < NT; ++t) {
        __syncthreads();
        if (t + 1 < NT) stage(k0base + (t + 1) * 64, p ^ 1);

#pragma unroll
        for (int ks = 0; ks < 2; ++ks) {
            const int slot = ((fq + ks * 4) ^ swz) * 8;
            short8 af[2], bf[4];
#pragma unroll
            for (int i = 0; i < 2; ++i)
                af[i] = *(const short8*)&As[p][(wr + i * 16 + fr) * 64 + slot];
#pragma unroll
            for (int j = 0; j < 4; ++j)
                bf[j] = *(const short8*)&Bs[p][(wc + j * 16 + fr) * 64 + slot];
#pragma unroll
            for (int i = 0; i < 2; ++i)
#pragma unroll
                for (int j = 0; j < 4; ++j)
                    acc[i][j] = __builtin_amdgcn_mfma_f32_16x16x32_bf16(af[i], bf[j], acc[i][j], 0, 0, 0);
        }
        p ^= 1;
    }

#pragma unroll
    for (int i = 0; i < 2; ++i) {
        int row = bm + wr + i * 16 + fq * 4;
#pragma unroll
        for (int j = 0; j < 4; ++j) {
            int col = bn + wc + j * 16 + fr;
#pragma unroll
            for (int r = 0; r < 4; ++r)
                atomicAdd(&C[(long)(row + r) * N + col], acc[i][j][r]);
        }
    }
}

// ---------------------------------------------------------------------------
// Differential flash attention + fused GroupNorm — r12-PROVEN version
// (80.0 µs, 0 bank conflicts, VGPR 88, 2 blocks/CU). 4 waves x 16q, full
// 64-key tiles, global_load_lds staging with XOR-chunk swizzle, K=32 PV via
// permlane merge, exp2-domain softmax, fused GN epilogue.
// ---------------------------------------------------------------------------
__global__ __launch_bounds__(256, 2)
void diff_attn(const u16* __restrict__ Qm, const u16* __restrict__ Km,
               const u16* __restrict__ Vt,
               const float* __restrict__ lq1, const float* __restrict__ lk1,
               const float* __restrict__ lq2, const float* __restrict__ lk2,
               const float* __restrict__ gw, const float* __restrict__ gb,
               u16* __restrict__ Y)
{
    __shared__ __attribute__((aligned(16))) u16 K1s[2][64 * 64];
    __shared__ __attribute__((aligned(16))) u16 K2s[2][64 * 64];
    __shared__ __attribute__((aligned(16))) u16 Vts[2][128 * 64];

    const int tid = threadIdx.x, lane = tid & 63, wave = tid >> 6;
    const int h = blockIdx.y;
    const int q0 = blockIdx.x * 64 + wave * 16;
    const int fr = lane & 15, qq = lane >> 4;
    const int fsw = fr & 7;

    const int grow = lane >> 3;
    const int gcol = ((lane & 7) ^ grow) * 8;

    float d1 = 0.f, d2 = 0.f;
    for (int i = 0; i < DH_NUM; ++i) {
        d1 += lq1[i] * lk1[i];
        d2 += lq2[i] * lk2[i];
    }
    const float lam = __expf(d1) - __expf(d2) + 0.8f;

    short8 q1f[2], q2f[2];
    {
        const u16* qb = Qm + (long)(q0 + fr) * D_DIM + h * 128;
        q1f[0] = *(const short8*)(qb + qq * 8);
        q1f[1] = *(const short8*)(qb + 32 + qq * 8);
        q2f[0] = *(const short8*)(qb + 64 + qq * 8);
        q2f[1] = *(const short8*)(qb + 96 + qq * 8);
    }

    f32x4 a1[8], a2[8];
    for (int n = 0; n < 8; ++n) { f32x4 zz = {0.f,0.f,0.f,0.f}; a1[n] = zz; a2[n] = zz; }
    float ls1 = 0.f, ls2 = 0.f;

    auto stage = [&](int kb, int b) {
        const long kbase = (long)(kb * 64) * D_DIM + h * 128;
#pragma unroll
        for (int g = 0; g < 2; ++g) {
            int r = wave * 16 + g * 8;
            gload16(Km + kbase + (long)(r + grow) * D_DIM + gcol,      &K1s[b][r * 64]);
            gload16(Km + kbase + (long)(r + grow) * D_DIM + 64 + gcol, &K2s[b][r * 64]);
        }
#pragma unroll
        for (int g = 0; g < 4; ++g) {
            int c = wave * 32 + g * 8;
            gload16(Vt + (long)(h * 128 + c + grow) * S_DIM + kb * 64 + gcol,
                    &Vts[b][c * 64]);
        }
    };

    stage(0, 0);
    int p = 0;

    for (int kb = 0; kb < S_DIM / 64; ++kb) {
        __syncthreads();                       // tile p staged & prev reads done
        const bool more = (kb + 1 < S_DIM / 64);
        if (more) stage(kb + 1, p ^ 1);        // prefetch hides under compute

        // jj indexes a 32-key window; jh its two 16-key S-chunks.
#pragma unroll
        for (int jj = 0; jj < 2; ++jj) {
            unsigned u1[2][2], u2[2][2];   // [jh][packed word]; all const-indexed
#pragma unroll
            for (int jh = 0; jh < 2; ++jh) {
                const int j = jj * 2 + jh;
                f32x4 s1 = {0.f,0.f,0.f,0.f}, s2 = {0.f,0.f,0.f,0.f};
#pragma unroll
                for (int ks = 0; ks < 2; ++ks) {
                    const int slot = ((ks * 4 + qq) ^ fsw) * 8;
                    short8 k1 = *(const short8*)&K1s[p][(j * 16 + fr) * 64 + slot];
                    short8 k2 = *(const short8*)&K2s[p][(j * 16 + fr) * 64 + slot];
                    s1 = __builtin_amdgcn_mfma_f32_16x16x32_bf16(k1, q1f[ks], s1, 0, 0, 0);
                    s2 = __builtin_amdgcn_mfma_f32_16x16x32_bf16(k2, q2f[ks], s2, 0, 0, 0);
                }
                float e1[4], e2[4];
#pragma unroll
                for (int r = 0; r < 4; ++r) {
                    e1[r] = EXP2(s1[r]);            // Q pre-scaled by log2e
                    e2[r] = EXP2(s2[r]);
                    ls1 += e1[r]; ls2 += e2[r];
                }
                u1[jh][0] = pk_bf16(e1[0], e1[1]); u1[jh][1] = pk_bf16(e1[2], e1[3]);
                u2[jh][0] = pk_bf16(e2[0], e2[1]); u2[jh][1] = pk_bf16(e2[2], e2[3]);
            }

            // Merge two 16-key P-chunks into K=32 B-fragments.
            // Lane group g holds keys {4g,4g+1}(w0)/{4g+2,4g+3}(w1) per chunk;
            // K=32 B-frag word w needs keys {8g+2w, 8g+2w+1}.
            // swap32+swap16 on (chunk0.w, chunk1.w) yields frag words w and w+2.
            union { short8 s; unsigned u[4]; } F1, F2;
            {
                unsigned x = u1[0][0], y = u1[1][0];
                lane_swap32(x, y); lane_swap16(x, y);
                F1.u[0] = x; F1.u[2] = y;
            }
            {
                unsigned x = u1[0][1], y = u1[1][1];
                lane_swap32(x, y); lane_swap16(x, y);
                F1.u[1] = x; F1.u[3] = y;
            }
            {
                unsigned x = u2[0][0], y = u2[1][0];
                lane_swap32(x, y); lane_swap16(x, y);
                F2.u[0] = x; F2.u[2] = y;
            }
            {
                unsigned x = u2[0][1], y = u2[1][1];
                lane_swap32(x, y); lane_swap16(x, y);
                F2.u[1] = x; F2.u[3] = y;
            }

            const int slotV = ((jj * 4 + qq) ^ fsw) * 8;
            __builtin_amdgcn_s_setprio(1);
#pragma unroll
            for (int n = 0; n < 8; ++n) {
                short8 vf = *(const short8*)&Vts[p][(n * 16 + fr) * 64 + slotV];
                a1[n] = __builtin_amdgcn_mfma_f32_16x16x32_bf16(vf, F1.s, a1[n], 0, 0, 0);
                a2[n] = __builtin_amdgcn_mfma_f32_16x16x32_bf16(vf, F2.s, a2[n], 0, 0, 0);
            }
            __builtin_amdgcn_s_setprio(0);
        }

        p ^= 1;
    }

    float L1 = ls1, L2 = ls2;
    L1 += __shfl_xor(L1, 16, 64); L1 += __shfl_xor(L1, 32, 64);
    L2 += __shfl_xor(L2, 16, 64); L2 += __shfl_xor(L2, 32, 64);
    const float i1 = 1.f / L1, i2 = lam / L2;

    float o[8][4], sum = 0.f, sq = 0.f;
#pragma unroll
    for (int n = 0; n < 8; ++n)
#pragma unroll
        for (int r = 0; r < 4; ++r) {
            float v = a1[n][r] * i1 - a2[n][r] * i2;
            o[n][r] = v; sum += v; sq += v * v;
        }
    sum += __shfl_xor(sum, 16, 64); sum += __shfl_xor(sum, 32, 64);
    sq  += __shfl_xor(sq, 16, 64);  sq  += __shfl_xor(sq, 32, 64);
    const float mean = sum * (1.f / 128.f);
    const float var = sq * (1.f / 128.f) - mean * mean;
    const float inv = rsqrtf(var + 1e-5f);

    const long yrow = (long)(q0 + fr) * D_DIM + h * 128;
#pragma unroll
    for (int n = 0; n < 8; ++n) {
        float4 g4 = *(const float4*)&gw[h * 128 + n * 16 + qq * 4];
        float4 b4 = *(const float4*)&gb[h * 128 + n * 16 + qq * 4];
        ushort4 st;
        st.x = f2bf(((o[n][0] - mean) * inv * g4.x + b4.x) * 0.2f);
        st.y = f2bf(((o[n][1] - mean) * inv * g4.y + b4.y) * 0.2f);
        st.z = f2bf(((o[n][2] - mean) * inv * g4.z + b4.z) * 0.2f);
        st.w = f2bf(((o[n][3] - mean) * inv * g4.w + b4.w) * 0.2f);
        *(ushort4*)&Y[yrow + n * 16 + qq * 4] = st;
    }
}

// ---------------------------------------------------------------------------
extern "C" void kernel_launch(void* const* d_in, const int* in_sizes, int n_in,
                              void* d_out, int out_size, void* d_ws, size_t ws_size,
                              hipStream_t stream)
{
    const float* x   = (const float*)d_in[0];
    const float* Wq  = (const float*)d_in[1];
    const float* Wk  = (const float*)d_in[2];
    const float* Wv  = (const float*)d_in[3];
    const float* Wo  = (const float*)d_in[4];
    const float* lq1 = (const float*)d_in[5];
    const float* lk1 = (const float*)d_in[6];
    const float* lq2 = (const float*)d_in[7];
    const float* lk2 = (const float*)d_in[8];
    const float* gw  = (const float*)d_in[9];
    const float* gb  = (const float*)d_in[10];

    char* ws = (char*)d_ws;
    const size_t SEG = (size_t)D_DIM * D_DIM * sizeof(u16);   // 8 MiB
    const dim3 tgrid(32, 32), agrid(32, 16), ogrid(32, 16, 2);

    if (ws_size >= 8 * SEG) {
        u16* XB  = (u16*)(ws + 0 * SEG);
        u16* WTq = (u16*)(ws + 1 * SEG);
        u16* WTk = (u16*)(ws + 2 * SEG);
        u16* WTv = (u16*)(ws + 3 * SEG);
        u16* Qb  = (u16*)(ws + 4 * SEG);
        u16* Kb  = (u16*)(ws + 5 * SEG);
        u16* Vt  = (u16*)(ws + 6 * SEG);
        u16* WTo = (u16*)(ws + 7 * SEG);
        u16* Yb  = WTk;   // dead after QKV GEMM

        prep4<<<dim3(1024, 1, 5), 256, 0, stream>>>(x, Wq, Wk, Wv, Wo,
                                                    XB, WTq, WTk, WTv, WTo);
        gemm128<<<dim3(16, 16, 3), 256, 0, stream>>>(XB, WTq, WTk, WTv,
                                                     Qb, Kb, Vt, 0);
        diff_attn<<<agrid, 256, 0, stream>>>(Qb, Kb, Vt, lq1, lk1, lq2, lk2,
                                             gw, gb, Yb);
        hipMemsetAsync(d_out, 0, out_size, stream);
        gemm_out<<<ogrid, 256, 0, stream>>>(Yb, WTo, (float*)d_out);
    } else if (ws_size >= 7 * SEG) {
        u16* XB  = (u16*)(ws + 0 * SEG);
        u16* WTq = (u16*)(ws + 1 * SEG);
        u16* WTk = (u16*)(ws + 2 * SEG);
        u16* WTv = (u16*)(ws + 3 * SEG);
        u16* Qb  = (u16*)(ws + 4 * SEG);
        u16* Kb  = (u16*)(ws + 5 * SEG);
        u16* Vt  = (u16*)(ws + 6 * SEG);
        u16* WTo = WTq;   // dead after QKV GEMM
        u16* Yb  = WTk;   // dead after QKV GEMM

        prep4<<<dim3(1024, 1, 4), 256, 0, stream>>>(x, Wq, Wk, Wv, Wo,
                                                    XB, WTq, WTk, WTv, WTq);
        gemm128<<<dim3(16, 16, 3), 256, 0, stream>>>(XB, WTq, WTk, WTv,
                                                     Qb, Kb, Vt, 0);
        transpose_fast<<<tgrid, 256, 0, stream>>>(Wo, WTo);
        diff_attn<<<agrid, 256, 0, stream>>>(Qb, Kb, Vt, lq1, lk1, lq2, lk2,
                                             gw, gb, Yb);
        hipMemsetAsync(d_out, 0, out_size, stream);
        gemm_out<<<ogrid, 256, 0, stream>>>(Yb, WTo, (float*)d_out);
    } else {
        u16* XB = (u16*)(ws + 0 * SEG);
        u16* WT = (u16*)(ws + 1 * SEG);
        u16* Qb = (u16*)(ws + 2 * SEG);
        u16* Kb = (u16*)(ws + 3 * SEG);
        u16* Vt = (u16*)(ws + 4 * SEG);

        cvt_bf16<<<4096, 256, 0, stream>>>(x, XB);
        transpose_fast<<<tgrid, 256, 0, stream>>>(Wq, WT);
        gemm128<<<dim3(16, 16, 1), 256, 0, stream>>>(XB, WT, WT, WT, Qb, Qb, Qb, 0);
        transpose_fast<<<tgrid, 256, 0, stream>>>(Wk, WT);
        gemm128<<<dim3(16, 16, 1), 256, 0, stream>>>(XB, WT, WT, WT, Kb, Kb, Kb, 1);
        transpose_fast<<<tgrid, 256, 0, stream>>>(Wv, WT);
        gemm128<<<dim3(16, 16, 1), 256, 0, stream>>>(XB, WT, WT, WT, Vt, Vt, Vt, 2);
        diff_attn<<<agrid, 256, 0, stream>>>(Qb, Kb, Vt, lq1, lk1, lq2, lk2,
                                             gw, gb, XB);
        transpose_fast<<<tgrid, 256, 0, stream>>>(Wo, WT);
        hipMemsetAsync(d_out, 0, out_size, stream);
        gemm_out<<<ogrid, 256, 0, stream>>>(XB, WT, (float*)d_out);
    }
}

// Round 8
// 293.487 us; speedup vs baseline: 1.2434x; 1.1063x over previous
//
#include <hip/hip_runtime.h>
#include <hip/hip_bf16.h>

typedef unsigned short u16;
typedef __attribute__((ext_vector_type(8))) short short8;   // 8 x bf16 bits
typedef __attribute__((ext_vector_type(4))) short short4v;  // 4 x bf16 bits
typedef __attribute__((ext_vector_type(4))) float f32x4;

#define S_DIM 2048
#define D_DIM 2048
#define H_NUM 16
#define DH_NUM 64

#if __has_builtin(__builtin_amdgcn_exp2f)
#define EXP2(x) __builtin_amdgcn_exp2f(x)
#else
#define EXP2(x) exp2f(x)
#endif

__device__ __forceinline__ u16 f2bf(float f) {
    union { float f; unsigned u; } x; x.f = f;
    unsigned r = x.u + 0x7fff + ((x.u >> 16) & 1);   // RNE
    return (u16)(r >> 16);
}

// pack 2 fp32 -> 2 bf16 (RNE) in one v_cvt_pk_bf16_f32
__device__ __forceinline__ unsigned pk_bf16(float a, float b) {
    union { __hip_bfloat162 h; unsigned u; } cv;
    float2 t; t.x = a; t.y = b;
    cv.h = __float22bfloat162_rn(t);
    return cv.u;
}

// register-pair lane swaps (gfx950): after swap32, a=[A0 A1 B0 B1], b=[A2 A3 B2 B3]
// (Ag = 16-lane group g of a). after swap16 on that: a=[A0 A2 B0 B2], b=[A1 A3 B1 B3].
__device__ __forceinline__ void lane_swap32(unsigned &a, unsigned &b) {
    asm("v_permlane32_swap_b32 %0, %1" : "+v"(a), "+v"(b));
}
__device__ __forceinline__ void lane_swap16(unsigned &a, unsigned &b) {
    asm("v_permlane16_swap_b32 %0, %1" : "+v"(a), "+v"(b));
}

// async global->LDS, 16B per lane; LDS dest = wave-uniform base + lane*16
__device__ __forceinline__ void gload16(const void* g, void* l) {
    __builtin_amdgcn_global_load_lds(
        (const __attribute__((address_space(1))) unsigned int*)g,
        (__attribute__((address_space(3))) unsigned int*)l, 16, 0, 0);
}

// ---------------------------------------------------------------------------
// Fast transpose body: 64x64 fp32 LDS tile, float4 reads, 16B bf16 stores.
// ---------------------------------------------------------------------------
__device__ __forceinline__ void transpose_body(const float* __restrict__ src,
                                               u16* __restrict__ dst,
                                               int tx, int ty, int t)
{
    __shared__ float tile[64][65];
    const int r0 = ty * 64, c0 = tx * 64;
#pragma unroll
    for (int p = 0; p < 4; ++p) {
        int r = p * 16 + (t >> 4), c = (t & 15) * 4;
        float4 v = *(const float4*)&src[(long)(r0 + r) * D_DIM + c0 + c];
        tile[r][c] = v.x; tile[r][c + 1] = v.y;
        tile[r][c + 2] = v.z; tile[r][c + 3] = v.w;
    }
    __syncthreads();
#pragma unroll
    for (int p = 0; p < 2; ++p) {
        int ch = t + p * 256;
        int i = ch >> 3, j0 = (ch & 7) * 8;
        short8 o;
#pragma unroll
        for (int jj = 0; jj < 8; ++jj)
            o[jj] = (short)f2bf(tile[j0 + jj][i]);
        *(short8*)&dst[(long)(c0 + i) * D_DIM + r0 + j0] = o;
    }
}

__global__ __launch_bounds__(256)
void transpose_fast(const float* __restrict__ src, u16* __restrict__ dst)
{
    transpose_body(src, dst, blockIdx.x, blockIdx.y, threadIdx.x);
}

// fused prep: z=0 cvt x->bf16, z=1..3 W^T (q/k/v), z=4 (optional) Wo^T
__global__ __launch_bounds__(256)
void prep4(const float* __restrict__ x,
           const float* __restrict__ Wq, const float* __restrict__ Wk,
           const float* __restrict__ Wv, const float* __restrict__ Wo,
           u16* __restrict__ XB, u16* T0, u16* T1, u16* T2, u16* T3)
{
    const int z = blockIdx.z, t = threadIdx.x, bx = blockIdx.x;
    if (z == 0) {
        long i0 = ((long)bx * 256 + t) * 16;
        short8 o0, o1;
#pragma unroll
        for (int j = 0; j < 2; ++j) {
            float4 a = *(const float4*)&x[i0 + j * 8];
            float4 b = *(const float4*)&x[i0 + j * 8 + 4];
            short8& o = j ? o1 : o0;
            o[0] = (short)f2bf(a.x); o[1] = (short)f2bf(a.y);
            o[2] = (short)f2bf(a.z); o[3] = (short)f2bf(a.w);
            o[4] = (short)f2bf(b.x); o[5] = (short)f2bf(b.y);
            o[6] = (short)f2bf(b.z); o[7] = (short)f2bf(b.w);
        }
        *(short8*)&XB[i0] = o0;
        *(short8*)&XB[i0 + 8] = o1;
    } else {
        const float* src = (z == 1) ? Wq : (z == 2) ? Wk : (z == 3) ? Wv : Wo;
        u16* dst         = (z == 1) ? T0 : (z == 2) ? T1 : (z == 3) ? T2 : T3;
        transpose_body(src, dst, bx & 31, bx >> 5, t);
    }
}

__global__ __launch_bounds__(256)
void cvt_bf16(const float* __restrict__ src, u16* __restrict__ dst)
{
    int i = (blockIdx.x * 256 + threadIdx.x) * 4;
    float4 v = *(const float4*)(src + i);
    ushort4 o;
    o.x = f2bf(v.x); o.y = f2bf(v.y); o.z = f2bf(v.z); o.w = f2bf(v.w);
    *(ushort4*)(dst + i) = o;
}

// ---------------------------------------------------------------------------
// 128x128-tile GEMM, BK=64 — r15-proven dbuf 2-phase loop (stage(t+1) issued
// BEFORE compute(t), ONE __syncthreads per K-step; LDS 64 KB, lb(256,2)).
// r18 adds an XCD-aware, z-fastest block remap (bijective, 768 = 8 XCDs x
// 96): each XCD's 96 blocks cover 2 bn-rows x 16 bm x 3 z, so its 6
// B-panels (3 MB) fit the 4 MB per-XCD L2 and each A-tile's 3 z-consumers
// are temporally adjacent (A staged once, reused for Wq/Wk/Wv). Index remap
// only — correctness-neutral. XOR-chunk swizzle staging as before. z0 -> Q
// (scaled 1/8*log2e), z1 -> K, z2 -> V^T via operand-swapped MFMA.
// NOTE: lb arg-2 must stay <= 2 (r16: lb(256,3) => 2x regression).
// ---------------------------------------------------------------------------
__global__ __launch_bounds__(256, 2)
void gemm128(const u16* __restrict__ A,
             const u16* B0, const u16* B1, const u16* B2,
             u16* C0, u16* C1, u16* C2, int zbase)
{
    const int Kd = D_DIM, N = D_DIM, M = S_DIM;

    int bx, by, z;
    if (gridDim.z == 3) {
        int b  = blockIdx.x + (blockIdx.y << 4) + (blockIdx.z << 8);
        int nb = (b & 7) * 96 + (b >> 3);      // chunked XCD remap
        z = nb % 3;
        int t = nb / 3;                         // z fastest -> A reuse
        bx = t & 15; by = t >> 4;
    } else {
        bx = blockIdx.x; by = blockIdx.y; z = zbase;
    }

    const u16* Bt = (z == 0) ? B0 : (z == 1) ? B1 : B2;
    u16* C        = (z == 0) ? C0 : (z == 1) ? C1 : C2;

    __shared__ __attribute__((aligned(16))) u16 As[2][128 * 64];
    __shared__ __attribute__((aligned(16))) u16 Bs[2][128 * 64];

    const int tid = threadIdx.x, lane = tid & 63, wave = tid >> 6;
    const int bm = bx * 128, bn = by * 128;

    const int grow = lane >> 3;
    const int gcol = ((lane & 7) ^ grow) * 8;

    const int wr = (wave >> 1) * 64, wc = (wave & 1) * 64;
    const int fr = lane & 15, fq = lane >> 4;
    const int swz = fr & 7;

    f32x4 acc[4][4];
    for (int i = 0; i < 4; ++i)
        for (int j = 0; j < 4; ++j) { f32x4 zz = {0.f,0.f,0.f,0.f}; acc[i][j] = zz; }

    auto stage = [&](int k0, int b) {
#pragma unroll
        for (int g = 0; g < 4; ++g) {
            int r = wave * 32 + g * 8;
            gload16(A + (long)(bm + r + grow) * Kd + k0 + gcol, &As[b][r * 64]);
            gload16(Bt + (long)(bn + r + grow) * Kd + k0 + gcol, &Bs[b][r * 64]);
        }
    };

    stage(0, 0);
    int p = 0;
    const int NT = Kd / 64;

    for (int t = 0; t < NT; ++t) {
        __syncthreads();                    // tile p staged; prev reads done
        if (t + 1 < NT) stage((t + 1) * 64, p ^ 1);   // in flight under compute

#pragma unroll
        for (int ks = 0; ks < 2; ++ks) {
            const int slot = ((fq + ks * 4) ^ swz) * 8;
            short8 af[4], bf[4];
#pragma unroll
            for (int i = 0; i < 4; ++i) {
                af[i] = *(const short8*)&As[p][(wr + i * 16 + fr) * 64 + slot];
                bf[i] = *(const short8*)&Bs[p][(wc + i * 16 + fr) * 64 + slot];
            }
            if (z == 2) {
#pragma unroll
                for (int i = 0; i < 4; ++i)
#pragma unroll
                    for (int j = 0; j < 4; ++j)
                        acc[i][j] = __builtin_amdgcn_mfma_f32_16x16x32_bf16(bf[j], af[i], acc[i][j], 0, 0, 0);
            } else {
#pragma unroll
                for (int i = 0; i < 4; ++i)
#pragma unroll
                    for (int j = 0; j < 4; ++j)
                        acc[i][j] = __builtin_amdgcn_mfma_f32_16x16x32_bf16(af[i], bf[j], acc[i][j], 0, 0, 0);
            }
        }
        p ^= 1;
    }

    if (z == 2) {
        // swapped layout: row (fq*4+r) = channel, col (fr) = token -> contig
#pragma unroll
        for (int i = 0; i < 4; ++i) {
            int tok = bm + wr + i * 16 + fr;
#pragma unroll
            for (int j = 0; j < 4; ++j) {
                int ch = bn + wc + j * 16 + fq * 4;
#pragma unroll
                for (int r = 0; r < 4; ++r)
                    C[(long)(ch + r) * M + tok] = f2bf(acc[i][j][r]);
            }
        }
    } else {
        const float sc = (z == 0) ? 0.125f * 1.44269504f : 1.0f;  // Q log2-domain
#pragma unroll
        for (int i = 0; i < 4; ++i) {
            int row = bm + wr + i * 16 + fq * 4;
#pragma unroll
            for (int j = 0; j < 4; ++j) {
                int col = bn + wc + j * 16 + fr;
#pragma unroll
                for (int r = 0; r < 4; ++r)
                    C[(long)(row + r) * N + col] = f2bf(acc[i][j][r] * sc);
            }
        }
    }
}

// ---------------------------------------------------------------------------
// 64x64-tile GEMM, fp32 output, BK=64. r18: full-residency form — 1024
// blocks, 16 KB LDS single-buffered, ~60 VGPR -> ~8 blocks/CU co-resident
// (entire grid resident, no tail) for this latency-bound kernel. Plain
// stores (r17's atomic K-split added write traffic and regressed). XCD
// swizzle (1024 % 8 == 0, bijective). lb(256,2) only.
// ---------------------------------------------------------------------------
__global__ __launch_bounds__(256, 2)
void gemm_out(const u16* __restrict__ A, const u16* __restrict__ Bt,
              float* __restrict__ C)
{
    const int Kd = D_DIM, N = D_DIM;

    __shared__ __attribute__((aligned(16))) u16 As[64 * 64];
    __shared__ __attribute__((aligned(16))) u16 Bs[64 * 64];

    const int b0 = blockIdx.x + (blockIdx.y << 5);
    const int nb = (b0 & 7) * 128 + (b0 >> 3);
    const int bm = (nb & 31) * 64, bn = (nb >> 5) * 64;

    const int tid = threadIdx.x, lane = tid & 63, wave = tid >> 6;

    const int grow = lane >> 3;
    const int gcol = ((lane & 7) ^ grow) * 8;

    const int wr = (wave >> 1) * 32, wc = (wave & 1) * 32;
    const int fr = lane & 15, fq = lane >> 4;
    const int swz = fr & 7;

    f32x4 acc[2][2];
    for (int i = 0; i < 2; ++i)
        for (int j = 0; j < 2; ++j) { f32x4 zz = {0.f,0.f,0.f,0.f}; acc[i][j] = zz; }

    for (int k0 = 0; k0 < Kd; k0 += 64) {
#pragma unroll
        for (int g = 0; g < 2; ++g) {
            int r = wave * 16 + g * 8;
            gload16(A + (long)(bm + r + grow) * Kd + k0 + gcol, &As[r * 64]);
            gload16(Bt + (long)(bn + r + grow) * Kd + k0 + gcol, &Bs[r * 64]);
        }
        __syncthreads();

#pragma unroll
        for (int ks = 0; ks < 2; ++ks) {
            const int slot = ((fq + ks * 4) ^ swz) * 8;
            short8 af[2], bf[2];
#pragma unroll
            for (int i = 0; i < 2; ++i) {
                af[i] = *(const short8*)&As[(wr + i * 16 + fr) * 64 + slot];
                bf[i] = *(const short8*)&Bs[(wc + i * 16 + fr) * 64 + slot];
            }
#pragma unroll
            for (int i = 0; i < 2; ++i)
#pragma unroll
                for (int j = 0; j < 2; ++j)
                    acc[i][j] = __builtin_amdgcn_mfma_f32_16x16x32_bf16(af[i], bf[j], acc[i][j], 0, 0, 0);
        }
        __syncthreads();
    }

#pragma unroll
    for (int i = 0; i < 2; ++i) {
        int row = bm + wr + i * 16 + fq * 4;
#pragma unroll
        for (int j = 0; j < 2; ++j) {
            int col = bn + wc + j * 16 + fr;
#pragma unroll
            for (int r = 0; r < 4; ++r)
                C[(long)(row + r) * N + col] = acc[i][j][r];
        }
    }
}

// ---------------------------------------------------------------------------
// Differential flash attention + fused GroupNorm — r12-PROVEN version
// (80.0 µs, 0 bank conflicts, VGPR 88, 2 blocks/CU). 4 waves x 16q, full
// 64-key tiles, global_load_lds staging with XOR-chunk swizzle, K=32 PV via
// permlane merge, exp2-domain softmax, fused GN epilogue.
// ---------------------------------------------------------------------------
__global__ __launch_bounds__(256, 2)
void diff_attn(const u16* __restrict__ Qm, const u16* __restrict__ Km,
               const u16* __restrict__ Vt,
               const float* __restrict__ lq1, const float* __restrict__ lk1,
               const float* __restrict__ lq2, const float* __restrict__ lk2,
               const float* __restrict__ gw, const float* __restrict__ gb,
               u16* __restrict__ Y)
{
    __shared__ __attribute__((aligned(16))) u16 K1s[2][64 * 64];
    __shared__ __attribute__((aligned(16))) u16 K2s[2][64 * 64];
    __shared__ __attribute__((aligned(16))) u16 Vts[2][128 * 64];

    const int tid = threadIdx.x, lane = tid & 63, wave = tid >> 6;
    const int h = blockIdx.y;
    const int q0 = blockIdx.x * 64 + wave * 16;
    const int fr = lane & 15, qq = lane >> 4;
    const int fsw = fr & 7;

    const int grow = lane >> 3;
    const int gcol = ((lane & 7) ^ grow) * 8;

    float d1 = 0.f, d2 = 0.f;
    for (int i = 0; i < DH_NUM; ++i) {
        d1 += lq1[i] * lk1[i];
        d2 += lq2[i] * lk2[i];
    }
    const float lam = __expf(d1) - __expf(d2) + 0.8f;

    short8 q1f[2], q2f[2];
    {
        const u16* qb = Qm + (long)(q0 + fr) * D_DIM + h * 128;
        q1f[0] = *(const short8*)(qb + qq * 8);
        q1f[1] = *(const short8*)(qb + 32 + qq * 8);
        q2f[0] = *(const short8*)(qb + 64 + qq * 8);
        q2f[1] = *(const short8*)(qb + 96 + qq * 8);
    }

    f32x4 a1[8], a2[8];
    for (int n = 0; n < 8; ++n) { f32x4 zz = {0.f,0.f,0.f,0.f}; a1[n] = zz; a2[n] = zz; }
    float ls1 = 0.f, ls2 = 0.f;

    auto stage = [&](int kb, int b) {
        const long kbase = (long)(kb * 64) * D_DIM + h * 128;
#pragma unroll
        for (int g = 0; g < 2; ++g) {
            int r = wave * 16 + g * 8;
            gload16(Km + kbase + (long)(r + grow) * D_DIM + gcol,      &K1s[b][r * 64]);
            gload16(Km + kbase + (long)(r + grow) * D_DIM + 64 + gcol, &K2s[b][r * 64]);
        }
#pragma unroll
        for (int g = 0; g < 4; ++g) {
            int c = wave * 32 + g * 8;
            gload16(Vt + (long)(h * 128 + c + grow) * S_DIM + kb * 64 + gcol,
                    &Vts[b][c * 64]);
        }
    };

    stage(0, 0);
    int p = 0;

    for (int kb = 0; kb < S_DIM / 64; ++kb) {
        __syncthreads();                       // tile p staged & prev reads done
        const bool more = (kb + 1 < S_DIM / 64);
        if (more) stage(kb + 1, p ^ 1);        // prefetch hides under compute

        // jj indexes a 32-key window; jh its two 16-key S-chunks.
#pragma unroll
        for (int jj = 0; jj < 2; ++jj) {
            unsigned u1[2][2], u2[2][2];   // [jh][packed word]; all const-indexed
#pragma unroll
            for (int jh = 0; jh < 2; ++jh) {
                const int j = jj * 2 + jh;
                f32x4 s1 = {0.f,0.f,0.f,0.f}, s2 = {0.f,0.f,0.f,0.f};
#pragma unroll
                for (int ks = 0; ks < 2; ++ks) {
                    const int slot = ((ks * 4 + qq) ^ fsw) * 8;
                    short8 k1 = *(const short8*)&K1s[p][(j * 16 + fr) * 64 + slot];
                    short8 k2 = *(const short8*)&K2s[p][(j * 16 + fr) * 64 + slot];
                    s1 = __builtin_amdgcn_mfma_f32_16x16x32_bf16(k1, q1f[ks], s1, 0, 0, 0);
                    s2 = __builtin_amdgcn_mfma_f32_16x16x32_bf16(k2, q2f[ks], s2, 0, 0, 0);
                }
                float e1[4], e2[4];
#pragma unroll
                for (int r = 0; r < 4; ++r) {
                    e1[r] = EXP2(s1[r]);            // Q pre-scaled by log2e
                    e2[r] = EXP2(s2[r]);
                    ls1 += e1[r]; ls2 += e2[r];
                }
                u1[jh][0] = pk_bf16(e1[0], e1[1]); u1[jh][1] = pk_bf16(e1[2], e1[3]);
                u2[jh][0] = pk_bf16(e2[0], e2[1]); u2[jh][1] = pk_bf16(e2[2], e2[3]);
            }

            // Merge two 16-key P-chunks into K=32 B-fragments.
            // Lane group g holds keys {4g,4g+1}(w0)/{4g+2,4g+3}(w1) per chunk;
            // K=32 B-frag word w needs keys {8g+2w, 8g+2w+1}.
            // swap32+swap16 on (chunk0.w, chunk1.w) yields frag words w and w+2.
            union { short8 s; unsigned u[4]; } F1, F2;
            {
                unsigned x = u1[0][0], y = u1[1][0];
                lane_swap32(x, y); lane_swap16(x, y);
                F1.u[0] = x; F1.u[2] = y;
            }
            {
                unsigned x = u1[0][1], y = u1[1][1];
                lane_swap32(x, y); lane_swap16(x, y);
                F1.u[1] = x; F1.u[3] = y;
            }
            {
                unsigned x = u2[0][0], y = u2[1][0];
                lane_swap32(x, y); lane_swap16(x, y);
                F2.u[0] = x; F2.u[2] = y;
            }
            {
                unsigned x = u2[0][1], y = u2[1][1];
                lane_swap32(x, y); lane_swap16(x, y);
                F2.u[1] = x; F2.u[3] = y;
            }

            const int slotV = ((jj * 4 + qq) ^ fsw) * 8;
            __builtin_amdgcn_s_setprio(1);
#pragma unroll
            for (int n = 0; n < 8; ++n) {
                short8 vf = *(const short8*)&Vts[p][(n * 16 + fr) * 64 + slotV];
                a1[n] = __builtin_amdgcn_mfma_f32_16x16x32_bf16(vf, F1.s, a1[n], 0, 0, 0);
                a2[n] = __builtin_amdgcn_mfma_f32_16x16x32_bf16(vf, F2.s, a2[n], 0, 0, 0);
            }
            __builtin_amdgcn_s_setprio(0);
        }

        p ^= 1;
    }

    float L1 = ls1, L2 = ls2;
    L1 += __shfl_xor(L1, 16, 64); L1 += __shfl_xor(L1, 32, 64);
    L2 += __shfl_xor(L2, 16, 64); L2 += __shfl_xor(L2, 32, 64);
    const float i1 = 1.f / L1, i2 = lam / L2;

    float o[8][4], sum = 0.f, sq = 0.f;
#pragma unroll
    for (int n = 0; n < 8; ++n)
#pragma unroll
        for (int r = 0; r < 4; ++r) {
            float v = a1[n][r] * i1 - a2[n][r] * i2;
            o[n][r] = v; sum += v; sq += v * v;
        }
    sum += __shfl_xor(sum, 16, 64); sum += __shfl_xor(sum, 32, 64);
    sq  += __shfl_xor(sq, 16, 64);  sq  += __shfl_xor(sq, 32, 64);
    const float mean = sum * (1.f / 128.f);
    const float var = sq * (1.f / 128.f) - mean * mean;
    const float inv = rsqrtf(var + 1e-5f);

    const long yrow = (long)(q0 + fr) * D_DIM + h * 128;
#pragma unroll
    for (int n = 0; n < 8; ++n) {
        float4 g4 = *(const float4*)&gw[h * 128 + n * 16 + qq * 4];
        float4 b4 = *(const float4*)&gb[h * 128 + n * 16 + qq * 4];
        ushort4 st;
        st.x = f2bf(((o[n][0] - mean) * inv * g4.x + b4.x) * 0.2f);
        st.y = f2bf(((o[n][1] - mean) * inv * g4.y + b4.y) * 0.2f);
        st.z = f2bf(((o[n][2] - mean) * inv * g4.z + b4.z) * 0.2f);
        st.w = f2bf(((o[n][3] - mean) * inv * g4.w + b4.w) * 0.2f);
        *(ushort4*)&Y[yrow + n * 16 + qq * 4] = st;
    }
}

// ---------------------------------------------------------------------------
extern "C" void kernel_launch(void* const* d_in, const int* in_sizes, int n_in,
                              void* d_out, int out_size, void* d_ws, size_t ws_size,
                              hipStream_t stream)
{
    const float* x   = (const float*)d_in[0];
    const float* Wq  = (const float*)d_in[1];
    const float* Wk  = (const float*)d_in[2];
    const float* Wv  = (const float*)d_in[3];
    const float* Wo  = (const float*)d_in[4];
    const float* lq1 = (const float*)d_in[5];
    const float* lk1 = (const float*)d_in[6];
    const float* lq2 = (const float*)d_in[7];
    const float* lk2 = (const float*)d_in[8];
    const float* gw  = (const float*)d_in[9];
    const float* gb  = (const float*)d_in[10];

    char* ws = (char*)d_ws;
    const size_t SEG = (size_t)D_DIM * D_DIM * sizeof(u16);   // 8 MiB
    const dim3 tgrid(32, 32), agrid(32, 16), ogrid(32, 32);

    if (ws_size >= 8 * SEG) {
        u16* XB  = (u16*)(ws + 0 * SEG);
        u16* WTq = (u16*)(ws + 1 * SEG);
        u16* WTk = (u16*)(ws + 2 * SEG);
        u16* WTv = (u16*)(ws + 3 * SEG);
        u16* Qb  = (u16*)(ws + 4 * SEG);
        u16* Kb  = (u16*)(ws + 5 * SEG);
        u16* Vt  = (u16*)(ws + 6 * SEG);
        u16* WTo = (u16*)(ws + 7 * SEG);
        u16* Yb  = WTk;   // dead after QKV GEMM

        prep4<<<dim3(1024, 1, 5), 256, 0, stream>>>(x, Wq, Wk, Wv, Wo,
                                                    XB, WTq, WTk, WTv, WTo);
        gemm128<<<dim3(16, 16, 3), 256, 0, stream>>>(XB, WTq, WTk, WTv,
                                                     Qb, Kb, Vt, 0);
        diff_attn<<<agrid, 256, 0, stream>>>(Qb, Kb, Vt, lq1, lk1, lq2, lk2,
                                             gw, gb, Yb);
        gemm_out<<<ogrid, 256, 0, stream>>>(Yb, WTo, (float*)d_out);
    } else if (ws_size >= 7 * SEG) {
        u16* XB  = (u16*)(ws + 0 * SEG);
        u16* WTq = (u16*)(ws + 1 * SEG);
        u16* WTk = (u16*)(ws + 2 * SEG);
        u16* WTv = (u16*)(ws + 3 * SEG);
        u16* Qb  = (u16*)(ws + 4 * SEG);
        u16* Kb  = (u16*)(ws + 5 * SEG);
        u16* Vt  = (u16*)(ws + 6 * SEG);
        u16* WTo = WTq;   // dead after QKV GEMM
        u16* Yb  = WTk;   // dead after QKV GEMM

        prep4<<<dim3(1024, 1, 4), 256, 0, stream>>>(x, Wq, Wk, Wv, Wo,
                                                    XB, WTq, WTk, WTv, WTq);
        gemm128<<<dim3(16, 16, 3), 256, 0, stream>>>(XB, WTq, WTk, WTv,
                                                     Qb, Kb, Vt, 0);
        transpose_fast<<<tgrid, 256, 0, stream>>>(Wo, WTo);
        diff_attn<<<agrid, 256, 0, stream>>>(Qb, Kb, Vt, lq1, lk1, lq2, lk2,
                                             gw, gb, Yb);
        gemm_out<<<ogrid, 256, 0, stream>>>(Yb, WTo, (float*)d_out);
    } else {
        u16* XB = (u16*)(ws + 0 * SEG);
        u16* WT = (u16*)(ws + 1 * SEG);
        u16* Qb = (u16*)(ws + 2 * SEG);
        u16* Kb = (u16*)(ws + 3 * SEG);
        u16* Vt = (u16*)(ws + 4 * SEG);

        cvt_bf16<<<4096, 256, 0, stream>>>(x, XB);
        transpose_fast<<<tgrid, 256, 0, stream>>>(Wq, WT);
        gemm128<<<dim3(16, 16, 1), 256, 0, stream>>>(XB, WT, WT, WT, Qb, Qb, Qb, 0);
        transpose_fast<<<tgrid, 256, 0, stream>>>(Wk, WT);
        gemm128<<<dim3(16, 16, 1), 256, 0, stream>>>(XB, WT, WT, WT, Kb, Kb, Kb, 1);
        transpose_fast<<<tgrid, 256, 0, stream>>>(Wv, WT);
        gemm128<<<dim3(16, 16, 1), 256, 0, stream>>>(XB, WT, WT, WT, Vt, Vt, Vt, 2);
        diff_attn<<<agrid, 256, 0, stream>>>(Qb, Kb, Vt, lq1, lk1, lq2, lk2,
                                             gw, gb, XB);
        transpose_fast<<<tgrid, 256, 0, stream>>>(Wo, WT);
        gemm_out<<<ogrid, 256, 0, stream>>>(XB, WT, (float*)d_out);
    }
}